// Round 1
// baseline (3316.408 us; speedup 1.0000x reference)
//
#include <hip/hip_runtime.h>
#include <math.h>

#define B_   32
#define P_   196
#define F_   2048
#define E_   512
#define H_   512
#define A_   512
#define V_   10000
#define T_   20
#define KIN  (E_ + F_)   // 2560

// ---------------------------------------------------------------------------
// Kernel 1: enc_proj[m, a] = features[m, :] . enc_W[a, :] + enc_b[a]
// M = 6272 (b*p), N = 512, K = 2048. Both operands K-major (row-major, ld=2048).
// Tile 128x64, 256 threads, 8x4 per thread, BK=32, k-major LDS for b128 reads.
// Grid (49, 8) exact, no edge cases.
// ---------------------------------------------------------------------------
__global__ __launch_bounds__(256)
void enc_proj_kernel(const float* __restrict__ feat,  // [6272, 2048]
                     const float* __restrict__ encW,  // [512, 2048]
                     const float* __restrict__ encB,  // [512]
                     float* __restrict__ encP)        // [6272, 512]
{
    __shared__ float As[32][128 + 4];  // k-major, pad 4 keeps 16B align
    __shared__ float Bs[32][64 + 4];

    const int tid = threadIdx.x;
    const int m0 = blockIdx.x * 128;
    const int n0 = blockIdx.y * 64;
    const int tm = (tid >> 4) * 8;    // 0..120
    const int tn = (tid & 15) * 4;    // 0..60

    float acc[8][4];
#pragma unroll
    for (int i = 0; i < 8; i++)
#pragma unroll
        for (int j = 0; j < 4; j++) acc[i][j] = 0.f;

    for (int k0 = 0; k0 < 2048; k0 += 32) {
        // Stage A tile 128x32 (1024 float4, 4 per thread), transposed to k-major
#pragma unroll
        for (int i = 0; i < 4; i++) {
            int r  = (tid >> 3) + i * 32;      // 0..127
            int c4 = tid & 7;                  // 0..7
            float4 v = *(const float4*)&feat[(size_t)(m0 + r) * 2048 + k0 + c4 * 4];
            As[c4 * 4 + 0][r] = v.x;
            As[c4 * 4 + 1][r] = v.y;
            As[c4 * 4 + 2][r] = v.z;
            As[c4 * 4 + 3][r] = v.w;
        }
        // Stage B tile 64x32 (512 float4, 2 per thread)
#pragma unroll
        for (int i = 0; i < 2; i++) {
            int r  = (tid >> 3) + i * 32;      // 0..63
            int c4 = tid & 7;
            float4 v = *(const float4*)&encW[(size_t)(n0 + r) * 2048 + k0 + c4 * 4];
            Bs[c4 * 4 + 0][r] = v.x;
            Bs[c4 * 4 + 1][r] = v.y;
            Bs[c4 * 4 + 2][r] = v.z;
            Bs[c4 * 4 + 3][r] = v.w;
        }
        __syncthreads();
#pragma unroll
        for (int kk = 0; kk < 32; kk++) {
            float a[8], b[4];
            *(float4*)&a[0] = *(float4*)&As[kk][tm];
            *(float4*)&a[4] = *(float4*)&As[kk][tm + 4];
            *(float4*)&b[0] = *(float4*)&Bs[kk][tn];
#pragma unroll
            for (int i = 0; i < 8; i++)
#pragma unroll
                for (int j = 0; j < 4; j++) acc[i][j] += a[i] * b[j];
        }
        __syncthreads();
    }

    float4 bb = *(const float4*)&encB[n0 + tn];
#pragma unroll
    for (int i = 0; i < 8; i++) {
        int m = m0 + tm + i;
        float4 o;
        o.x = acc[i][0] + bb.x;
        o.y = acc[i][1] + bb.y;
        o.z = acc[i][2] + bb.z;
        o.w = acc[i][3] + bb.w;
        *(float4*)&encP[(size_t)m * A_ + n0 + tn] = o;
    }
}

// ---------------------------------------------------------------------------
// Kernel 2 (fused): blocks 0..31  -> attention for step t (needs h_t):
//   dec_proj, energies, softmax -> alpha; also x_t embedding copy into lstm_in.
// blocks 32..344 -> vocab FC for step t-1 (needs the same h_t): out[b,t-1,:].
// Launched for t = 0..20; attention skipped at t=20, FC skipped at t=0.
// ---------------------------------------------------------------------------
__global__ __launch_bounds__(256)
void attn_fc_kernel(int t,
                    const float* __restrict__ h,        // h_t [32,512]
                    const float* __restrict__ encP,     // [32,196,512]
                    const float* __restrict__ dec_W,    // [512,512]
                    const float* __restrict__ dec_b,    // [512]
                    const float* __restrict__ full_W,   // [512]
                    const float* __restrict__ full_b,   // [1]
                    float* __restrict__ alpha,          // [32,196]
                    float* __restrict__ lstm_in,        // [32,2560]
                    const float* __restrict__ emb,      // [10000,512]
                    const int* __restrict__ captions,   // [32,20]
                    const float* __restrict__ fc_W,     // [10000,512]
                    const float* __restrict__ fc_b,     // [10000]
                    float* __restrict__ out)            // [32,20,10000]
{
    __shared__ float smem[5280];
    const int tid = threadIdx.x;

    if (blockIdx.x < 32) {
        // ----------------- attention for step t -----------------
        if (t >= T_) return;
        const int b = blockIdx.x;
        float* hs  = smem;          // 512
        float* fws = smem + 512;    // 512
        float* dps = smem + 1024;   // 512
        float* es  = smem + 1536;   // 196

        if (tid < 128) {
            *(float4*)&hs[tid * 4] = *(const float4*)&h[b * H_ + tid * 4];
            int cap = captions[b * T_ + t];
            *(float4*)&lstm_in[b * KIN + tid * 4] =
                *(const float4*)&emb[(size_t)cap * E_ + tid * 4];
        } else {
            int i = tid - 128;
            *(float4*)&fws[i * 4] = *(const float4*)&full_W[i * 4];
        }
        __syncthreads();

        // dec_proj: 2 outputs per thread (a = tid, tid+256)
        {
            const float* w1 = dec_W + (size_t)tid * H_;
            const float* w2 = dec_W + (size_t)(tid + 256) * H_;
            float4 a1 = {0, 0, 0, 0}, a2 = {0, 0, 0, 0};
            for (int k = 0; k < H_; k += 4) {
                float4 hv = *(float4*)&hs[k];
                float4 x1 = *(const float4*)&w1[k];
                float4 x2 = *(const float4*)&w2[k];
                a1.x += x1.x * hv.x; a1.y += x1.y * hv.y;
                a1.z += x1.z * hv.z; a1.w += x1.w * hv.w;
                a2.x += x2.x * hv.x; a2.y += x2.y * hv.y;
                a2.z += x2.z * hv.z; a2.w += x2.w * hv.w;
            }
            dps[tid]       = (a1.x + a1.y + a1.z + a1.w) + dec_b[tid];
            dps[tid + 256] = (a2.x + a2.y + a2.z + a2.w) + dec_b[tid + 256];
        }
        __syncthreads();

        // energies: wave w handles p = w + 4*i; lane-split over A with shuffle reduce
        const int wave = tid >> 6, lane = tid & 63;
        const float fb0 = full_b[0];
        for (int i = 0; i < 49; i++) {
            int p = wave + 4 * i;
            const float* ep = encP + (size_t)(b * P_ + p) * A_;
            float s = 0.f;
#pragma unroll
            for (int q = 0; q < 8; q++) {
                int a = lane + 64 * q;          // stride-64: coalesced + conflict-free
                s += fmaxf(ep[a] + dps[a], 0.f) * fws[a];
            }
#pragma unroll
            for (int off = 32; off > 0; off >>= 1) s += __shfl_xor(s, off, 64);
            if (lane == 0) es[p] = s + fb0;
        }
        __syncthreads();

        // softmax over 196 by wave 0
        if (tid < 64) {
            float v[4]; int pv[4]; int n = 0;
            for (int q = 0; q < 4; q++) {
                int p = tid + 64 * q;
                if (p < P_) { pv[n] = p; v[n] = es[p]; n++; }
            }
            float m = -1e30f;
            for (int q = 0; q < n; q++) m = fmaxf(m, v[q]);
#pragma unroll
            for (int off = 32; off > 0; off >>= 1) m = fmaxf(m, __shfl_xor(m, off, 64));
            float ssum = 0.f;
            for (int q = 0; q < n; q++) { v[q] = expf(v[q] - m); ssum += v[q]; }
#pragma unroll
            for (int off = 32; off > 0; off >>= 1) ssum += __shfl_xor(ssum, off, 64);
            float rinv = 1.f / ssum;
            for (int q = 0; q < n; q++) alpha[b * P_ + pv[q]] = v[q] * rinv;
        }
    } else {
        // ----------------- FC for step t-1 -----------------
        if (t == 0) return;
        const int fb = blockIdx.x - 32;
        const int v0 = fb * 32;
        float* h_s = smem;          // 32 x 132
        float* res = smem + 4224;   // 32 x 33
        const int b  = tid & 31;
        const int vl = tid >> 5;    // 0..7

        int v[4]; const float* wr[4];
#pragma unroll
        for (int s = 0; s < 4; s++) {
            v[s] = v0 + vl + 8 * s;
            int vc = v[s] < V_ ? v[s] : V_ - 1;
            wr[s] = fc_W + (size_t)vc * H_;
        }
        float4 a0 = {0,0,0,0}, a1 = {0,0,0,0}, a2 = {0,0,0,0}, a3 = {0,0,0,0};

        for (int k0 = 0; k0 < H_; k0 += 128) {
#pragma unroll
            for (int i = 0; i < 4; i++) {
                int idx = tid + i * 256;       // 0..1023, 32 f4 per row
                int rb = idx >> 5, rc = idx & 31;
                *(float4*)&h_s[rb * 132 + rc * 4] =
                    *(const float4*)&h[rb * H_ + k0 + rc * 4];
            }
            __syncthreads();
#pragma unroll 8
            for (int kk = 0; kk < 128; kk += 4) {
                float4 x  = *(float4*)&h_s[b * 132 + kk];
                float4 w0 = *(const float4*)&wr[0][k0 + kk];
                float4 w1 = *(const float4*)&wr[1][k0 + kk];
                float4 w2 = *(const float4*)&wr[2][k0 + kk];
                float4 w3 = *(const float4*)&wr[3][k0 + kk];
                a0.x += w0.x * x.x; a0.y += w0.y * x.y; a0.z += w0.z * x.z; a0.w += w0.w * x.w;
                a1.x += w1.x * x.x; a1.y += w1.y * x.y; a1.z += w1.z * x.z; a1.w += w1.w * x.w;
                a2.x += w2.x * x.x; a2.y += w2.y * x.y; a2.z += w2.z * x.z; a2.w += w2.w * x.w;
                a3.x += w3.x * x.x; a3.y += w3.y * x.y; a3.z += w3.z * x.z; a3.w += w3.w * x.w;
            }
            __syncthreads();
        }
        res[(vl + 8 * 0) * 33 + b] = a0.x + a0.y + a0.z + a0.w;
        res[(vl + 8 * 1) * 33 + b] = a1.x + a1.y + a1.z + a1.w;
        res[(vl + 8 * 2) * 33 + b] = a2.x + a2.y + a2.z + a2.w;
        res[(vl + 8 * 3) * 33 + b] = a3.x + a3.y + a3.z + a3.w;
        __syncthreads();

        // transposed write: thread (b2, c4) stores 4 consecutive v for one b
        const int b2 = tid >> 3, c4 = tid & 7;
        const int vbase = v0 + c4 * 4;
        if (vbase + 3 < V_) {
            float4 o;
            o.x = res[(c4 * 4 + 0) * 33 + b2] + fc_b[vbase + 0];
            o.y = res[(c4 * 4 + 1) * 33 + b2] + fc_b[vbase + 1];
            o.z = res[(c4 * 4 + 2) * 33 + b2] + fc_b[vbase + 2];
            o.w = res[(c4 * 4 + 3) * 33 + b2] + fc_b[vbase + 3];
            *(float4*)&out[(size_t)b2 * T_ * V_ + (size_t)(t - 1) * V_ + vbase] = o;
        }
    }
}

// ---------------------------------------------------------------------------
// Kernel 3: context[b, f] = sum_p alpha[b,p] * features[b,p,f] -> lstm_in[:,512+f]
// Grid (8, 32): block = (f-chunk of 256, b). Fully coalesced feature reads.
// ---------------------------------------------------------------------------
__global__ __launch_bounds__(256)
void ctx_kernel(const float* __restrict__ feat,
                const float* __restrict__ alpha,
                float* __restrict__ lstm_in)
{
    __shared__ float als[P_];
    const int b  = blockIdx.y;
    const int f0 = blockIdx.x * 256;
    const int tid = threadIdx.x;
    if (tid < P_) als[tid] = alpha[b * P_ + tid];
    __syncthreads();
    const float* fp = feat + (size_t)b * P_ * F_ + f0 + tid;
    float a0 = 0, a1 = 0, a2 = 0, a3 = 0;
    for (int p = 0; p < P_; p += 4) {        // 196 = 49*4 exact
        a0 += als[p]     * fp[(size_t)p * F_];
        a1 += als[p + 1] * fp[(size_t)(p + 1) * F_];
        a2 += als[p + 2] * fp[(size_t)(p + 2) * F_];
        a3 += als[p + 3] * fp[(size_t)(p + 3) * F_];
    }
    lstm_in[b * KIN + E_ + f0 + tid] = a0 + a1 + a2 + a3;
}

// ---------------------------------------------------------------------------
// Kernel 4: gates + LSTM pointwise, fused.
// 256 blocks; block bx owns u-tile {2u} x 4 gates x 32 b = 256 outputs.
// Thread: b = tid&31, ul = (tid>>5)&1, g = tid>>6; one K=3072 dot each.
// h double-buffered (h_in read by all blocks, h_out written) - no race.
// c is read+written only by the owning block -> safe in place.
// ---------------------------------------------------------------------------
__global__ __launch_bounds__(256)
void gates_pw_kernel(const float* __restrict__ W_ih, const float* __restrict__ b_ih,
                     const float* __restrict__ W_hh, const float* __restrict__ b_hh,
                     const float* __restrict__ lstm_in,
                     const float* __restrict__ h_in,
                     float* __restrict__ h_out, float* __restrict__ c)
{
    __shared__ float xs[32][68];
    __shared__ float accs[256];
    const int tid = threadIdx.x;
    const int b  = tid & 31;
    const int ul = (tid >> 5) & 1;
    const int g  = tid >> 6;
    const int u0 = blockIdx.x * 2;
    const int u  = u0 + ul;
    const int j  = g * H_ + u;

    float4 a4 = {0, 0, 0, 0};
    const float* wrow = W_ih + (size_t)j * KIN;
    for (int k0 = 0; k0 < KIN; k0 += 64) {
#pragma unroll
        for (int i = 0; i < 2; i++) {
            int idx = tid + i * 256;           // 0..511, 16 f4 per row
            int rb = idx >> 4, rc = idx & 15;
            *(float4*)&xs[rb][rc * 4] =
                *(const float4*)&lstm_in[rb * KIN + k0 + rc * 4];
        }
        __syncthreads();
#pragma unroll
        for (int kk = 0; kk < 64; kk += 4) {
            float4 w = *(const float4*)&wrow[k0 + kk];
            float4 x = *(float4*)&xs[b][kk];
            a4.x += w.x * x.x; a4.y += w.y * x.y;
            a4.z += w.z * x.z; a4.w += w.w * x.w;
        }
        __syncthreads();
    }
    const float* wrow2 = W_hh + (size_t)j * H_;
    for (int k0 = 0; k0 < H_; k0 += 64) {
#pragma unroll
        for (int i = 0; i < 2; i++) {
            int idx = tid + i * 256;
            int rb = idx >> 4, rc = idx & 15;
            *(float4*)&xs[rb][rc * 4] =
                *(const float4*)&h_in[rb * H_ + k0 + rc * 4];
        }
        __syncthreads();
#pragma unroll
        for (int kk = 0; kk < 64; kk += 4) {
            float4 w = *(const float4*)&wrow2[k0 + kk];
            float4 x = *(float4*)&xs[b][kk];
            a4.x += w.x * x.x; a4.y += w.y * x.y;
            a4.z += w.z * x.z; a4.w += w.w * x.w;
        }
        __syncthreads();
    }
    accs[tid] = a4.x + a4.y + a4.z + a4.w + b_ih[j] + b_hh[j];
    __syncthreads();

    if (tid < 64) {
        const int b2 = tid & 31, ul2 = tid >> 5;
        const int uu = u0 + ul2;
        float ai = accs[      ul2 * 32 + b2];
        float af = accs[ 64 + ul2 * 32 + b2];
        float ag = accs[128 + ul2 * 32 + b2];
        float ao = accs[192 + ul2 * 32 + b2];
        float ig = 1.f / (1.f + expf(-ai));
        float fg = 1.f / (1.f + expf(-af));
        float gg = tanhf(ag);
        float og = 1.f / (1.f + expf(-ao));
        float cold = c[b2 * H_ + uu];
        float cn = fg * cold + ig * gg;
        float hn = og * tanhf(cn);
        c[b2 * H_ + uu]    = cn;
        h_out[b2 * H_ + uu] = hn;
    }
}

// ---------------------------------------------------------------------------
extern "C" void kernel_launch(void* const* d_in, const int* in_sizes, int n_in,
                              void* d_out, int out_size, void* d_ws, size_t ws_size,
                              hipStream_t stream)
{
    (void)in_sizes; (void)n_in; (void)out_size; (void)ws_size;
    const float* feat    = (const float*)d_in[0];
    const int*   caps    = (const int*)  d_in[1];
    const float* emb     = (const float*)d_in[2];
    const float* W_ih    = (const float*)d_in[3];
    const float* b_ih    = (const float*)d_in[4];
    const float* W_hh    = (const float*)d_in[5];
    const float* b_hh    = (const float*)d_in[6];
    const float* fc_W    = (const float*)d_in[7];
    const float* fc_b    = (const float*)d_in[8];
    const float* enc_W   = (const float*)d_in[9];
    const float* enc_b   = (const float*)d_in[10];
    const float* dec_W   = (const float*)d_in[11];
    const float* dec_b   = (const float*)d_in[12];
    const float* full_W  = (const float*)d_in[13];
    const float* full_b  = (const float*)d_in[14];
    float* out = (float*)d_out;

    // workspace layout (floats): ~13.4 MB total
    float* ws      = (float*)d_ws;
    float* encP    = ws;                       // 6272*512 = 3,211,264
    float* alpha   = encP + 3211264;           // 6,272 (pad 6400)
    float* lstm_in = alpha + 6400;             // 81,920
    float* h0      = lstm_in + 81920;          // 16,384
    float* cbuf    = h0 + 16384;               // 16,384  (contiguous with h0)
    float* h1      = cbuf + 16384;             // 16,384  (fully written at t=0)

    // h_0 = 0, c_0 = 0 (re-poisoned to 0xAA before every replay)
    hipMemsetAsync(h0, 0, (size_t)2 * B_ * H_ * sizeof(float), stream);

    enc_proj_kernel<<<dim3(49, 8), 256, 0, stream>>>(feat, enc_W, enc_b, encP);

    for (int t = 0; t <= T_; t++) {
        float* hcur  = (t & 1) ? h1 : h0;   // h_t
        float* hnext = (t & 1) ? h0 : h1;   // h_{t+1}
        attn_fc_kernel<<<32 + 313, 256, 0, stream>>>(
            t, hcur, encP, dec_W, dec_b, full_W, full_b,
            alpha, lstm_in, emb, caps, fc_W, fc_b, out);
        if (t < T_) {
            ctx_kernel<<<dim3(8, 32), 256, 0, stream>>>(feat, alpha, lstm_in);
            gates_pw_kernel<<<256, 256, 0, stream>>>(
                W_ih, b_ih, W_hh, b_hh, lstm_in, hcur, hnext, cbuf);
        }
    }
}

// Round 2
// 2482.570 us; speedup vs baseline: 1.3359x; 1.3359x over previous
//
#include <hip/hip_runtime.h>
#include <math.h>

#define B_   32
#define P_   196
#define F_   2048
#define E_   512
#define H_   512
#define V_   10000
#define T_   20
#define KIN  (E_ + F_)   // 2560

// ---------------------------------------------------------------------------
// Unified f32 GEMM: C[m,n] = A[m,:].B[n,:] + bias[n]   (both K-major)
// 64x64 tile, 256 thr, 4x4/thread, BK=32, XOR-swizzled k-major LDS
// (swizzle makes staging scatter-writes 2-way max = free, keeps b128 reads).
// mode 0: crow = m (enc_proj).  mode 1: crow = (m&31)*20 + (m>>5) (batched FC,
// A rows are [t][b] but out rows are [b][t]).
// M must be a multiple of 64 (6272 and 640 both are). N guarded.
// ---------------------------------------------------------------------------
__global__ __launch_bounds__(256)
void gemm_nt_kernel(const float* __restrict__ A, const float* __restrict__ B,
                    const float* __restrict__ bias, float* __restrict__ C,
                    int K, int N, int ldc, int mode)
{
    __shared__ float As[32][64];
    __shared__ float Bs[32][64];
    const int tid = threadIdx.x;
    const int m0 = blockIdx.x * 64;
    const int n0 = blockIdx.y * 64;
    const int tx = tid & 15, ty = tid >> 4;

    float acc[4][4];
#pragma unroll
    for (int i = 0; i < 4; i++)
#pragma unroll
        for (int j = 0; j < 4; j++) acc[i][j] = 0.f;

    const int r  = tid >> 3;              // 0..31
    const int c4 = tid & 7;               // 0..7
    const int kb = c4 * 4;
    const int fst = (c4 & 3) << 3;        // store swizzle = ((k>>2)&3)<<3

    for (int k0 = 0; k0 < K; k0 += 32) {
#pragma unroll
        for (int i = 0; i < 2; i++) {
            int rr = r + i * 32;
            float4 av = *(const float4*)&A[(size_t)(m0 + rr) * K + k0 + kb];
            int brow = n0 + rr; if (brow >= N) brow = N - 1;
            float4 bv = *(const float4*)&B[(size_t)brow * K + k0 + kb];
            int cc = rr ^ fst;
            As[kb + 0][cc] = av.x; As[kb + 1][cc] = av.y;
            As[kb + 2][cc] = av.z; As[kb + 3][cc] = av.w;
            Bs[kb + 0][cc] = bv.x; Bs[kb + 1][cc] = bv.y;
            Bs[kb + 2][cc] = bv.z; Bs[kb + 3][cc] = bv.w;
        }
        __syncthreads();
#pragma unroll
        for (int kk = 0; kk < 32; kk++) {
            const int fs = ((kk >> 2) & 3) << 3;
            float4 a4 = *(const float4*)&As[kk][(ty * 4) ^ fs];
            float4 b4 = *(const float4*)&Bs[kk][(tx * 4) ^ fs];
            float a[4] = {a4.x, a4.y, a4.z, a4.w};
            float b[4] = {b4.x, b4.y, b4.z, b4.w};
#pragma unroll
            for (int i = 0; i < 4; i++)
#pragma unroll
                for (int j = 0; j < 4; j++) acc[i][j] += a[i] * b[j];
        }
        __syncthreads();
    }

    const int n = n0 + tx * 4;
    float bz[4];
#pragma unroll
    for (int j = 0; j < 4; j++) {
        int nj = n + j; if (nj >= N) nj = N - 1;
        bz[j] = bias[nj];
    }
#pragma unroll
    for (int i = 0; i < 4; i++) {
        int m = m0 + ty * 4 + i;
        int crow = mode ? ((m & 31) * 20 + (m >> 5)) : m;
        float* cp = C + (size_t)crow * ldc + n;
        if (n + 3 < N) {
            float4 o;
            o.x = acc[i][0] + bz[0]; o.y = acc[i][1] + bz[1];
            o.z = acc[i][2] + bz[2]; o.w = acc[i][3] + bz[3];
            *(float4*)cp = o;
        } else {
#pragma unroll
            for (int j = 0; j < 4; j++)
                if (n + j < N) cp[j] = acc[i][j] + bz[j];
        }
    }
}

// ---------------------------------------------------------------------------
// Per-step kernel A: 32 blocks (one per batch b).
//  phase 0: LSTM pointwise  h_t, c_t from gbuf (gates preact of step t-1)
//           h_t -> LDS + hseq[t];  t==0: h=0 (slot 0 pre-memset);
//           t==T_: store h and exit (no attention).
//  phase 2: dec_proj (dps) with 16-lane-group coalesced dec_W reads + shfl.
//  phase 3: energies e_p = relu(encP+dps).full_W  (coalesced encP reads).
//  phase 4: softmax -> alpha.   Also copies x_t embedding into lstm_in.
// ---------------------------------------------------------------------------
__global__ __launch_bounds__(256)
void attn_step_kernel(int t,
                      const float* __restrict__ gbuf,    // [32][2048]
                      float* __restrict__ cbuf,          // [32][512]
                      float* __restrict__ hseq,          // [21][32][512]
                      const float* __restrict__ encP,    // [32][196][512]
                      const float* __restrict__ dec_W,   // [512][512]
                      const float* __restrict__ dec_b,   // [512]
                      const float* __restrict__ full_W,  // [512]
                      const float* __restrict__ full_b,  // [1]
                      float* __restrict__ alpha,         // [32][196]
                      float* __restrict__ lstm_in,       // [32][2560]
                      const float* __restrict__ emb,     // [10000][512]
                      const int* __restrict__ captions)  // [32][20]
{
    __shared__ float hs[512];
    __shared__ float fws[512];
    __shared__ float dps[512];
    __shared__ float es[P_];

    const int tid = threadIdx.x;
    const int b = blockIdx.x;

    // ---- phase 0: pointwise ----
    if (t == 0) {
        for (int u = tid; u < H_; u += 256) hs[u] = 0.f;
    } else {
        for (int u = tid; u < H_; u += 256) {
            float gi = gbuf[b * 2048 + u];
            float gf = gbuf[b * 2048 + 512 + u];
            float gg = gbuf[b * 2048 + 1024 + u];
            float go = gbuf[b * 2048 + 1536 + u];
            float ig = 1.f / (1.f + expf(-gi));
            float fg = 1.f / (1.f + expf(-gf));
            float g_ = tanhf(gg);
            float og = 1.f / (1.f + expf(-go));
            float cold = (t == 1) ? 0.f : cbuf[b * H_ + u];
            float cn = fg * cold + ig * g_;
            float hn = og * tanhf(cn);
            cbuf[b * H_ + u] = cn;
            hs[u] = hn;
            hseq[(size_t)t * 16384 + b * H_ + u] = hn;
        }
    }
    if (t >= T_) return;

    // ---- phase 1: stage full_W, copy embedding ----
    if (tid < 128) {
        *(float4*)&fws[tid * 4] = *(const float4*)&full_W[tid * 4];
        int cap = captions[b * T_ + t];
        *(float4*)&lstm_in[b * KIN + tid * 4] =
            *(const float4*)&emb[(size_t)cap * E_ + tid * 4];
    }
    __syncthreads();

    const int lane = tid & 63, wave = tid >> 6;
    const int g16 = lane >> 4;   // 0..3
    const int gl  = lane & 15;   // 0..15

    // ---- phase 2: dps[a] = hs . dec_W[a,:] + dec_b[a] ----
#pragma unroll 4
    for (int q = 0; q < 32; q++) {
        int a = wave * 128 + q * 4 + g16;
        const float* wr = dec_W + (size_t)a * H_;
        float s = 0.f;
#pragma unroll
        for (int j = 0; j < 8; j++) {
            float4 wv = *(const float4*)&wr[j * 64 + gl * 4];
            float4 hv = *(const float4*)&hs[j * 64 + gl * 4];
            s += wv.x * hv.x + wv.y * hv.y + wv.z * hv.z + wv.w * hv.w;
        }
        s += __shfl_xor(s, 1, 64); s += __shfl_xor(s, 2, 64);
        s += __shfl_xor(s, 4, 64); s += __shfl_xor(s, 8, 64);
        if (gl == 0) dps[a] = s + dec_b[a];
    }
    __syncthreads();

    // ---- phase 3: energies ----
    const float fb0 = full_b[0];
    for (int i = 0; i < 13; i++) {
        int q = wave + 4 * i;
        if (q >= 49) break;
        int p = q * 4 + g16;
        const float* ep = encP + ((size_t)b * P_ + p) * H_;
        float s = 0.f;
#pragma unroll
        for (int j = 0; j < 8; j++) {
            float4 ev = *(const float4*)&ep[j * 64 + gl * 4];
            float4 dv = *(const float4*)&dps[j * 64 + gl * 4];
            float4 fv = *(const float4*)&fws[j * 64 + gl * 4];
            s += fmaxf(ev.x + dv.x, 0.f) * fv.x + fmaxf(ev.y + dv.y, 0.f) * fv.y
               + fmaxf(ev.z + dv.z, 0.f) * fv.z + fmaxf(ev.w + dv.w, 0.f) * fv.w;
        }
        s += __shfl_xor(s, 1, 64); s += __shfl_xor(s, 2, 64);
        s += __shfl_xor(s, 4, 64); s += __shfl_xor(s, 8, 64);
        if (gl == 0) es[p] = s + fb0;
    }
    __syncthreads();

    // ---- phase 4: softmax over 196 (wave 0) ----
    if (tid < 64) {
        float v[4]; int pv[4]; int n = 0;
        for (int q = 0; q < 4; q++) {
            int p = tid + 64 * q;
            if (p < P_) { pv[n] = p; v[n] = es[p]; n++; }
        }
        float m = -1e30f;
        for (int q = 0; q < n; q++) m = fmaxf(m, v[q]);
#pragma unroll
        for (int off = 32; off > 0; off >>= 1) m = fmaxf(m, __shfl_xor(m, off, 64));
        float ssum = 0.f;
        for (int q = 0; q < n; q++) { v[q] = expf(v[q] - m); ssum += v[q]; }
#pragma unroll
        for (int off = 32; off > 0; off >>= 1) ssum += __shfl_xor(ssum, off, 64);
        float rinv = 1.f / ssum;
        for (int q = 0; q < n; q++) alpha[b * P_ + pv[q]] = v[q] * rinv;
    }
}

// ---------------------------------------------------------------------------
// Per-step kernel B: context. grid (4,32) x 128 thr, float4 streams.
// ---------------------------------------------------------------------------
__global__ __launch_bounds__(128)
void ctx_kernel(const float* __restrict__ feat,
                const float* __restrict__ alpha,
                float* __restrict__ lstm_in)
{
    __shared__ float als[P_];
    const int b  = blockIdx.y;
    const int f0 = blockIdx.x * 512;
    const int tid = threadIdx.x;
    als[tid] = alpha[b * P_ + tid];
    if (tid < P_ - 128) als[128 + tid] = alpha[b * P_ + 128 + tid];
    __syncthreads();
    const float* fp = feat + (size_t)b * P_ * F_ + f0 + tid * 4;
    float4 a0 = {0, 0, 0, 0};
#pragma unroll 4
    for (int p = 0; p < P_; p++) {
        float4 v = *(const float4*)&fp[(size_t)p * F_];
        float al = als[p];
        a0.x += al * v.x; a0.y += al * v.y; a0.z += al * v.z; a0.w += al * v.w;
    }
    *(float4*)&lstm_in[b * KIN + E_ + f0 + tid * 4] = a0;
}

// ---------------------------------------------------------------------------
// Per-step kernel C: gates preact GEMM. 256 blocks x 256 thr.
// Block owns 8 rows of [W_ih|W_hh] (j = bx*8 + wave*2 + {0,1}); wave computes
// 2 rows x all 32 b.  x = [lstm_in(2560) | h_t(512)] staged in LDS per
// 256-wide chunk; W rows read coalesced along K. Writes gbuf[b][j].
// ---------------------------------------------------------------------------
__global__ __launch_bounds__(256)
void gates_kernel(int t,
                  const float* __restrict__ W_ih, const float* __restrict__ b_ih,
                  const float* __restrict__ W_hh, const float* __restrict__ b_hh,
                  const float* __restrict__ lstm_in,
                  const float* __restrict__ hseq,
                  float* __restrict__ gbuf)
{
    __shared__ float xs[32][256];
    __shared__ float red[4][32][66];
    const int tid = threadIdx.x;
    const int wave = tid >> 6, lane = tid & 63;
    const int j0 = blockIdx.x * 8 + wave * 2;

    float acc0[32], acc1[32];
#pragma unroll
    for (int i = 0; i < 32; i++) { acc0[i] = 0.f; acc1[i] = 0.f; }

    for (int ch = 0; ch < 12; ch++) {
        const int k0 = ch * 256;
#pragma unroll
        for (int i = 0; i < 8; i++) {
            int idx = tid + i * 256;
            int bb = idx >> 6, kc = idx & 63;
            float4 v;
            if (ch < 10) v = *(const float4*)&lstm_in[bb * KIN + k0 + kc * 4];
            else v = *(const float4*)&hseq[(size_t)t * 16384 + bb * H_ + (k0 - KIN) + kc * 4];
            *(float4*)&xs[bb][kc * 4] = v;
        }
        __syncthreads();
        float4 w0, w1;
        if (ch < 10) {
            w0 = *(const float4*)&W_ih[(size_t)j0 * KIN + k0 + lane * 4];
            w1 = *(const float4*)&W_ih[(size_t)(j0 + 1) * KIN + k0 + lane * 4];
        } else {
            w0 = *(const float4*)&W_hh[(size_t)j0 * H_ + (k0 - KIN) + lane * 4];
            w1 = *(const float4*)&W_hh[(size_t)(j0 + 1) * H_ + (k0 - KIN) + lane * 4];
        }
#pragma unroll
        for (int bb = 0; bb < 32; bb++) {
            float4 x = *(float4*)&xs[bb][lane * 4];
            acc0[bb] += w0.x * x.x + w0.y * x.y + w0.z * x.z + w0.w * x.w;
            acc1[bb] += w1.x * x.x + w1.y * x.y + w1.z * x.z + w1.w * x.w;
        }
        __syncthreads();
    }

    // cross-lane reduce via LDS (66-pad -> 2-way max on read)
#pragma unroll
    for (int bb = 0; bb < 32; bb++) red[wave][bb][lane] = acc0[bb];
    __syncthreads();
    float s0 = 0.f;
    if (lane < 32) {
#pragma unroll 8
        for (int i = 0; i < 64; i++) s0 += red[wave][lane][i];
    }
    __syncthreads();
#pragma unroll
    for (int bb = 0; bb < 32; bb++) red[wave][bb][lane] = acc1[bb];
    __syncthreads();
    if (lane < 32) {
        float s1 = 0.f;
#pragma unroll 8
        for (int i = 0; i < 64; i++) s1 += red[wave][lane][i];
        gbuf[lane * 2048 + j0]     = s0 + b_ih[j0] + b_hh[j0];
        gbuf[lane * 2048 + j0 + 1] = s1 + b_ih[j0 + 1] + b_hh[j0 + 1];
    }
}

// ---------------------------------------------------------------------------
extern "C" void kernel_launch(void* const* d_in, const int* in_sizes, int n_in,
                              void* d_out, int out_size, void* d_ws, size_t ws_size,
                              hipStream_t stream)
{
    (void)in_sizes; (void)n_in; (void)out_size; (void)ws_size;
    const float* feat   = (const float*)d_in[0];
    const int*   caps   = (const int*)  d_in[1];
    const float* emb    = (const float*)d_in[2];
    const float* W_ih   = (const float*)d_in[3];
    const float* b_ih   = (const float*)d_in[4];
    const float* W_hh   = (const float*)d_in[5];
    const float* b_hh   = (const float*)d_in[6];
    const float* fc_W   = (const float*)d_in[7];
    const float* fc_b   = (const float*)d_in[8];
    const float* enc_W  = (const float*)d_in[9];
    const float* enc_b  = (const float*)d_in[10];
    const float* dec_W  = (const float*)d_in[11];
    const float* dec_b  = (const float*)d_in[12];
    const float* full_W = (const float*)d_in[13];
    const float* full_b = (const float*)d_in[14];
    float* out = (float*)d_out;

    // workspace layout (floats), ~14.9 MB
    float* ws      = (float*)d_ws;
    float* encP    = ws;                    // 3,211,264
    float* hseq    = encP + 3211264;        // 21*32*512 = 344,064
    float* gbuf    = hseq + 344064;         // 65,536
    float* cbuf    = gbuf + 65536;          // 16,384
    float* lstm_in = cbuf + 16384;          // 81,920
    float* alpha   = lstm_in + 81920;       // 6,272

    // h_0 = 0 (hseq slot 0); ws is re-poisoned before every replay
    hipMemsetAsync(hseq, 0, (size_t)B_ * H_ * sizeof(float), stream);

    // encoder projection: [6272,2048] x [512,2048]^T
    gemm_nt_kernel<<<dim3(98, 8), 256, 0, stream>>>(
        feat, enc_W, enc_b, encP, F_, 512, 512, 0);

    for (int t = 0; t <= T_; t++) {
        attn_step_kernel<<<32, 256, 0, stream>>>(
            t, gbuf, cbuf, hseq, encP, dec_W, dec_b, full_W, full_b,
            alpha, lstm_in, emb, caps);
        if (t < T_) {
            ctx_kernel<<<dim3(4, 32), 128, 0, stream>>>(feat, alpha, lstm_in);
            gates_kernel<<<256, 256, 0, stream>>>(
                t, W_ih, b_ih, W_hh, b_hh, lstm_in, hseq, gbuf);
        }
    }

    // batched vocab FC over all 20 steps: [640,512] x [10000,512]^T
    gemm_nt_kernel<<<dim3(10, 157), 256, 0, stream>>>(
        hseq + 16384, fc_W, fc_b, out, H_, V_, V_, 1);
}

// Round 3
// 2220.256 us; speedup vs baseline: 1.4937x; 1.1181x over previous
//
#include <hip/hip_runtime.h>
#include <math.h>

#define B_   32
#define P_   196
#define F_   2048
#define E_   512
#define H_   512
#define V_   10000
#define T_   20
#define KIN  (E_ + F_)   // 2560

typedef unsigned short ushort_t;
typedef ushort_t u16x8 __attribute__((ext_vector_type(8)));
typedef ushort_t u16x4 __attribute__((ext_vector_type(4)));
typedef short    bf16x8 __attribute__((ext_vector_type(8)));
typedef float    f32x4  __attribute__((ext_vector_type(4)));

__device__ __forceinline__ ushort_t bf_rne(float x) {
    union { float f; unsigned u; } v; v.f = x;
    unsigned r = v.u + 0x7FFFu + ((v.u >> 16) & 1u);
    return (ushort_t)(r >> 16);
}
__device__ __forceinline__ float b2f(ushort_t u) {
    union { unsigned u; float f; } v; v.u = ((unsigned)u) << 16;
    return v.f;
}

// ---------------------------------------------------------------------------
// f32 -> bf16 (RNE) converter. 8 elems/thread, exact grids (all sizes %2048==0).
// ---------------------------------------------------------------------------
__global__ __launch_bounds__(256)
void cvt_bf16_kernel(const float* __restrict__ s, ushort_t* __restrict__ d)
{
    int i = blockIdx.x * 256 + threadIdx.x;
    float4 a = *(const float4*)&s[(size_t)i * 8];
    float4 b = *(const float4*)&s[(size_t)i * 8 + 4];
    u16x8 o;
    o[0] = bf_rne(a.x); o[1] = bf_rne(a.y); o[2] = bf_rne(a.z); o[3] = bf_rne(a.w);
    o[4] = bf_rne(b.x); o[5] = bf_rne(b.y); o[6] = bf_rne(b.z); o[7] = bf_rne(b.w);
    *(u16x8*)&d[(size_t)i * 8] = o;
}

// ---------------------------------------------------------------------------
// bf16 MFMA GEMM: C[m,n] = A[m,:].B[n,:] + bias[n], A/B bf16 K-major.
// 128x128 tile, 256 thr = 4 waves, each wave 64x64 via 4x4 of 16x16x32 MFMA.
// mode 0: store bf16 to Cb (encP), N=512 exact.
// mode 1: store f32 to Cf with row remap crow=(m&31)*20+(m>>5), guard n<N.
// ---------------------------------------------------------------------------
__global__ __launch_bounds__(256)
void mfma_gemm_kernel(const ushort_t* __restrict__ A, const ushort_t* __restrict__ B,
                      const float* __restrict__ bias, ushort_t* __restrict__ Cb,
                      float* __restrict__ Cf, int K, int N, int mode)
{
    __shared__ ushort_t As[128][32];
    __shared__ ushort_t Bs[128][32];
    const int tid = threadIdx.x;
    const int m0 = blockIdx.x * 128, n0 = blockIdx.y * 128;
    const int wave = tid >> 6, lane = tid & 63;
    const int wm = (wave & 1) * 64, wn = (wave >> 1) * 64;
    const int lm = lane & 15, lk = (lane >> 4) * 8;

    f32x4 acc[4][4];
#pragma unroll
    for (int mt = 0; mt < 4; mt++)
#pragma unroll
        for (int nt = 0; nt < 4; nt++)
#pragma unroll
            for (int r = 0; r < 4; r++) acc[mt][nt][r] = 0.f;

    for (int k0 = 0; k0 < K; k0 += 32) {
#pragma unroll
        for (int i = 0; i < 2; i++) {
            int gi  = tid + i * 256;
            int row = gi >> 2;
            int gr  = (gi & 3) * 8;
            *(u16x8*)&As[row][gr] = *(const u16x8*)&A[(size_t)(m0 + row) * K + k0 + gr];
            int brow = n0 + row; if (brow >= N) brow = N - 1;
            *(u16x8*)&Bs[row][gr] = *(const u16x8*)&B[(size_t)brow * K + k0 + gr];
        }
        __syncthreads();
        bf16x8 af[4], bv[4];
#pragma unroll
        for (int mt = 0; mt < 4; mt++)
            af[mt] = *(const bf16x8*)&As[wm + mt * 16 + lm][lk];
#pragma unroll
        for (int nt = 0; nt < 4; nt++)
            bv[nt] = *(const bf16x8*)&Bs[wn + nt * 16 + lm][lk];
#pragma unroll
        for (int mt = 0; mt < 4; mt++)
#pragma unroll
            for (int nt = 0; nt < 4; nt++)
                acc[mt][nt] = __builtin_amdgcn_mfma_f32_16x16x32_bf16(
                    af[mt], bv[nt], acc[mt][nt], 0, 0, 0);
        __syncthreads();
    }

    const int rb = (lane >> 4) * 4;
#pragma unroll
    for (int nt = 0; nt < 4; nt++) {
        int n = n0 + wn + nt * 16 + lm;
        int nc = n < N ? n : N - 1;
        float bz = bias[nc];
#pragma unroll
        for (int mt = 0; mt < 4; mt++) {
            int mbase = m0 + wm + mt * 16 + rb;
#pragma unroll
            for (int r = 0; r < 4; r++) {
                float v = acc[mt][nt][r] + bz;
                int m = mbase + r;
                if (mode == 0) {
                    Cb[(size_t)m * N + n] = bf_rne(v);
                } else if (n < N) {
                    int crow = (m & 31) * 20 + (m >> 5);
                    Cf[(size_t)crow * N + n] = v;
                }
            }
        }
    }
}

// ---------------------------------------------------------------------------
// Per-step kernel A: 32 blocks (one per b).
//  phase 0: LSTM pointwise from gbuf -> h_t (LDS hs + hseq f32 + hseqB bf16), c in place.
//  phase 2: dps = h . dec_W^T + dec_b   (dec_W bf16, 16-lane-group + shfl)
//  phase 3: energies from encP (bf16)
//  phase 4: softmax -> alpha.  Also copies x_t embedding into lstm_in.
// ---------------------------------------------------------------------------
__global__ __launch_bounds__(256)
void attn_step_kernel(int t,
                      const float* __restrict__ gbuf,
                      float* __restrict__ cbuf,
                      float* __restrict__ hseq,
                      ushort_t* __restrict__ hseqB,
                      const ushort_t* __restrict__ encPB,
                      const ushort_t* __restrict__ decWB,
                      const float* __restrict__ dec_b,
                      const float* __restrict__ full_W,
                      const float* __restrict__ full_b,
                      float* __restrict__ alpha,
                      float* __restrict__ lstm_in,
                      const float* __restrict__ emb,
                      const int* __restrict__ captions)
{
    __shared__ float hs[512];
    __shared__ float fws[512];
    __shared__ float dps[512];
    __shared__ float es[P_];

    const int tid = threadIdx.x;
    const int b = blockIdx.x;

    // ---- phase 0: pointwise ----
    if (t == 0) {
        for (int u = tid; u < H_; u += 256) hs[u] = 0.f;
    } else {
        for (int u = tid; u < H_; u += 256) {
            float gi = gbuf[b * 2048 + u];
            float gf = gbuf[b * 2048 + 512 + u];
            float gg = gbuf[b * 2048 + 1024 + u];
            float go = gbuf[b * 2048 + 1536 + u];
            float ig = 1.f / (1.f + expf(-gi));
            float fg = 1.f / (1.f + expf(-gf));
            float g_ = tanhf(gg);
            float og = 1.f / (1.f + expf(-go));
            float cold = (t == 1) ? 0.f : cbuf[b * H_ + u];
            float cn = fg * cold + ig * g_;
            float hn = og * tanhf(cn);
            cbuf[b * H_ + u] = cn;
            hs[u] = hn;
            hseq[(size_t)t * 16384 + b * H_ + u]  = hn;
            hseqB[(size_t)t * 16384 + b * H_ + u] = bf_rne(hn);
        }
    }
    if (t >= T_) return;

    // ---- phase 1: stage full_W, copy embedding ----
    if (tid < 128) {
        *(float4*)&fws[tid * 4] = *(const float4*)&full_W[tid * 4];
        int cap = captions[b * T_ + t];
        *(float4*)&lstm_in[b * KIN + tid * 4] =
            *(const float4*)&emb[(size_t)cap * E_ + tid * 4];
    }
    __syncthreads();

    const int lane = tid & 63, wave = tid >> 6;
    const int g16 = lane >> 4;   // 0..3
    const int gl  = lane & 15;   // 0..15

    // ---- phase 2: dps[a] = hs . dec_W[a,:] + dec_b[a]  (bf16 W) ----
#pragma unroll 4
    for (int q = 0; q < 32; q++) {
        int a = wave * 128 + q * 4 + g16;
        const ushort_t* wr = decWB + (size_t)a * 512;
        float s = 0.f;
#pragma unroll
        for (int j = 0; j < 4; j++) {
            u16x8 wv = *(const u16x8*)&wr[j * 128 + gl * 8];
            float4 h0 = *(float4*)&hs[j * 128 + gl * 8];
            float4 h1 = *(float4*)&hs[j * 128 + gl * 8 + 4];
            s += b2f(wv[0]) * h0.x + b2f(wv[1]) * h0.y
               + b2f(wv[2]) * h0.z + b2f(wv[3]) * h0.w
               + b2f(wv[4]) * h1.x + b2f(wv[5]) * h1.y
               + b2f(wv[6]) * h1.z + b2f(wv[7]) * h1.w;
        }
        s += __shfl_xor(s, 1, 64); s += __shfl_xor(s, 2, 64);
        s += __shfl_xor(s, 4, 64); s += __shfl_xor(s, 8, 64);
        if (gl == 0) dps[a] = s + dec_b[a];
    }
    __syncthreads();

    // ---- phase 3: energies (encP bf16) ----
    const float fb0 = full_b[0];
    for (int i = 0; i < 13; i++) {
        int q = wave + 4 * i;
        if (q >= 49) break;
        int p = q * 4 + g16;
        const ushort_t* ep = encPB + ((size_t)(b * P_) + p) * 512;
        float s = 0.f;
#pragma unroll
        for (int j = 0; j < 4; j++) {
            u16x8 ev = *(const u16x8*)&ep[j * 128 + gl * 8];
            float4 d0 = *(float4*)&dps[j * 128 + gl * 8];
            float4 d1 = *(float4*)&dps[j * 128 + gl * 8 + 4];
            float4 f0 = *(float4*)&fws[j * 128 + gl * 8];
            float4 f1 = *(float4*)&fws[j * 128 + gl * 8 + 4];
            s += fmaxf(b2f(ev[0]) + d0.x, 0.f) * f0.x
               + fmaxf(b2f(ev[1]) + d0.y, 0.f) * f0.y
               + fmaxf(b2f(ev[2]) + d0.z, 0.f) * f0.z
               + fmaxf(b2f(ev[3]) + d0.w, 0.f) * f0.w
               + fmaxf(b2f(ev[4]) + d1.x, 0.f) * f1.x
               + fmaxf(b2f(ev[5]) + d1.y, 0.f) * f1.y
               + fmaxf(b2f(ev[6]) + d1.z, 0.f) * f1.z
               + fmaxf(b2f(ev[7]) + d1.w, 0.f) * f1.w;
        }
        s += __shfl_xor(s, 1, 64); s += __shfl_xor(s, 2, 64);
        s += __shfl_xor(s, 4, 64); s += __shfl_xor(s, 8, 64);
        if (gl == 0) es[p] = s + fb0;
    }
    __syncthreads();

    // ---- phase 4: softmax over 196 (wave 0) ----
    if (tid < 64) {
        float v[4]; int pv[4]; int n = 0;
        for (int q = 0; q < 4; q++) {
            int p = tid + 64 * q;
            if (p < P_) { pv[n] = p; v[n] = es[p]; n++; }
        }
        float m = -1e30f;
        for (int q = 0; q < n; q++) m = fmaxf(m, v[q]);
#pragma unroll
        for (int off = 32; off > 0; off >>= 1) m = fmaxf(m, __shfl_xor(m, off, 64));
        float ssum = 0.f;
        for (int q = 0; q < n; q++) { v[q] = expf(v[q] - m); ssum += v[q]; }
#pragma unroll
        for (int off = 32; off > 0; off >>= 1) ssum += __shfl_xor(ssum, off, 64);
        float rinv = 1.f / ssum;
        for (int q = 0; q < n; q++) alpha[b * P_ + pv[q]] = v[q] * rinv;
    }
}

// ---------------------------------------------------------------------------
// Per-step kernel B: context (f32 feat, L3-resident). grid (4,32) x 128 thr.
// ---------------------------------------------------------------------------
__global__ __launch_bounds__(128)
void ctx_kernel(const float* __restrict__ feat,
                const float* __restrict__ alpha,
                float* __restrict__ lstm_in)
{
    __shared__ float als[P_];
    const int b  = blockIdx.y;
    const int f0 = blockIdx.x * 512;
    const int tid = threadIdx.x;
    als[tid] = alpha[b * P_ + tid];
    if (tid < P_ - 128) als[128 + tid] = alpha[b * P_ + 128 + tid];
    __syncthreads();
    const float* fp = feat + (size_t)b * P_ * F_ + f0 + tid * 4;
    float4 a0 = {0, 0, 0, 0};
#pragma unroll 4
    for (int p = 0; p < P_; p++) {
        float4 v = *(const float4*)&fp[(size_t)p * F_];
        float al = als[p];
        a0.x += al * v.x; a0.y += al * v.y; a0.z += al * v.z; a0.w += al * v.w;
    }
    *(float4*)&lstm_in[b * KIN + E_ + f0 + tid * 4] = a0;
}

// ---------------------------------------------------------------------------
// Per-step kernel C: gates preact GEMM, W in bf16, x/h in f32.
// 256 blocks x 256 thr; wave computes 2 rows x 32 b.
// ---------------------------------------------------------------------------
__global__ __launch_bounds__(256)
void gates_kernel(int t,
                  const ushort_t* __restrict__ WihB, const float* __restrict__ b_ih,
                  const ushort_t* __restrict__ WhhB, const float* __restrict__ b_hh,
                  const float* __restrict__ lstm_in,
                  const float* __restrict__ hseq,
                  float* __restrict__ gbuf)
{
    __shared__ float xs[32][256];
    __shared__ float red[4][32][66];
    const int tid = threadIdx.x;
    const int wave = tid >> 6, lane = tid & 63;
    const int j0 = blockIdx.x * 8 + wave * 2;

    float acc0[32], acc1[32];
#pragma unroll
    for (int i = 0; i < 32; i++) { acc0[i] = 0.f; acc1[i] = 0.f; }

    for (int ch = 0; ch < 12; ch++) {
        const int k0 = ch * 256;
#pragma unroll
        for (int i = 0; i < 8; i++) {
            int idx = tid + i * 256;
            int bb = idx >> 6, kc = idx & 63;
            float4 v;
            if (ch < 10) v = *(const float4*)&lstm_in[bb * KIN + k0 + kc * 4];
            else v = *(const float4*)&hseq[(size_t)t * 16384 + bb * H_ + (k0 - KIN) + kc * 4];
            *(float4*)&xs[bb][kc * 4] = v;
        }
        __syncthreads();
        u16x4 w0, w1;
        if (ch < 10) {
            w0 = *(const u16x4*)&WihB[(size_t)j0 * KIN + k0 + lane * 4];
            w1 = *(const u16x4*)&WihB[(size_t)(j0 + 1) * KIN + k0 + lane * 4];
        } else {
            w0 = *(const u16x4*)&WhhB[(size_t)j0 * H_ + (k0 - KIN) + lane * 4];
            w1 = *(const u16x4*)&WhhB[(size_t)(j0 + 1) * H_ + (k0 - KIN) + lane * 4];
        }
        float w0x = b2f(w0[0]), w0y = b2f(w0[1]), w0z = b2f(w0[2]), w0w = b2f(w0[3]);
        float w1x = b2f(w1[0]), w1y = b2f(w1[1]), w1z = b2f(w1[2]), w1w = b2f(w1[3]);
#pragma unroll
        for (int bb = 0; bb < 32; bb++) {
            float4 x = *(float4*)&xs[bb][lane * 4];
            acc0[bb] += w0x * x.x + w0y * x.y + w0z * x.z + w0w * x.w;
            acc1[bb] += w1x * x.x + w1y * x.y + w1z * x.z + w1w * x.w;
        }
        __syncthreads();
    }

#pragma unroll
    for (int bb = 0; bb < 32; bb++) red[wave][bb][lane] = acc0[bb];
    __syncthreads();
    float s0 = 0.f;
    if (lane < 32) {
#pragma unroll 8
        for (int i = 0; i < 64; i++) s0 += red[wave][lane][i];
    }
    __syncthreads();
#pragma unroll
    for (int bb = 0; bb < 32; bb++) red[wave][bb][lane] = acc1[bb];
    __syncthreads();
    if (lane < 32) {
        float s1 = 0.f;
#pragma unroll 8
        for (int i = 0; i < 64; i++) s1 += red[wave][lane][i];
        gbuf[lane * 2048 + j0]     = s0 + b_ih[j0] + b_hh[j0];
        gbuf[lane * 2048 + j0 + 1] = s1 + b_ih[j0 + 1] + b_hh[j0 + 1];
    }
}

// ---------------------------------------------------------------------------
extern "C" void kernel_launch(void* const* d_in, const int* in_sizes, int n_in,
                              void* d_out, int out_size, void* d_ws, size_t ws_size,
                              hipStream_t stream)
{
    (void)in_sizes; (void)n_in; (void)out_size; (void)ws_size;
    const float* feat   = (const float*)d_in[0];
    const int*   caps   = (const int*)  d_in[1];
    const float* emb    = (const float*)d_in[2];
    const float* W_ih   = (const float*)d_in[3];
    const float* b_ih   = (const float*)d_in[4];
    const float* W_hh   = (const float*)d_in[5];
    const float* b_hh   = (const float*)d_in[6];
    const float* fc_W   = (const float*)d_in[7];
    const float* fc_b   = (const float*)d_in[8];
    const float* enc_W  = (const float*)d_in[9];
    const float* enc_b  = (const float*)d_in[10];
    const float* dec_W  = (const float*)d_in[11];
    const float* dec_b  = (const float*)d_in[12];
    const float* full_W = (const float*)d_in[13];
    const float* full_b = (const float*)d_in[14];
    float* out = (float*)d_out;

    // workspace carve (~60.4 MB)
    char* wsb = (char*)d_ws;
    ushort_t* featB = (ushort_t*)wsb;  wsb += 25690112;  // 6272*2048
    ushort_t* encWB = (ushort_t*)wsb;  wsb += 2097152;   // 512*2048
    ushort_t* fcWB  = (ushort_t*)wsb;  wsb += 10240000;  // 10000*512
    ushort_t* decWB = (ushort_t*)wsb;  wsb += 524288;    // 512*512
    ushort_t* WihB  = (ushort_t*)wsb;  wsb += 10485760;  // 2048*2560
    ushort_t* WhhB  = (ushort_t*)wsb;  wsb += 2097152;   // 2048*512
    ushort_t* encPB = (ushort_t*)wsb;  wsb += 6422528;   // 6272*512
    ushort_t* hseqB = (ushort_t*)wsb;  wsb += 688128;    // 21*32*512
    float* hseq     = (float*)wsb;     wsb += 1376256;   // 21*32*512
    float* gbuf     = (float*)wsb;     wsb += 262144;    // 32*2048
    float* cbuf     = (float*)wsb;     wsb += 131072;    // 32*512 (+slack)
    float* lstm_in  = (float*)wsb;     wsb += 327680;    // 32*2560
    float* alpha    = (float*)wsb;     wsb += 25088;     // 32*196

    // h_0 = 0 for gates at t=0
    hipMemsetAsync(hseq, 0, 65536, stream);

    // bf16 conversions (exact grids; every size divisible by 2048)
    cvt_bf16_kernel<<<6272, 256, 0, stream>>>(feat,  featB);
    cvt_bf16_kernel<<<512,  256, 0, stream>>>(enc_W, encWB);
    cvt_bf16_kernel<<<2500, 256, 0, stream>>>(fc_W,  fcWB);
    cvt_bf16_kernel<<<128,  256, 0, stream>>>(dec_W, decWB);
    cvt_bf16_kernel<<<2560, 256, 0, stream>>>(W_ih,  WihB);
    cvt_bf16_kernel<<<512,  256, 0, stream>>>(W_hh,  WhhB);

    // encoder projection: [6272,2048] x [512,2048]^T -> encPB (bf16)
    mfma_gemm_kernel<<<dim3(49, 4), 256, 0, stream>>>(
        featB, encWB, enc_b, encPB, nullptr, F_, 512, 0);

    for (int t = 0; t <= T_; t++) {
        attn_step_kernel<<<32, 256, 0, stream>>>(
            t, gbuf, cbuf, hseq, hseqB, encPB, decWB, dec_b, full_W, full_b,
            alpha, lstm_in, emb, caps);
        if (t < T_) {
            ctx_kernel<<<dim3(4, 32), 128, 0, stream>>>(feat, alpha, lstm_in);
            gates_kernel<<<256, 256, 0, stream>>>(
                t, WihB, b_ih, WhhB, b_hh, lstm_in, hseq, gbuf);
        }
    }

    // batched vocab FC over all 20 steps: [640,512] x [10000,512]^T -> out (f32)
    mfma_gemm_kernel<<<dim3(5, 79), 256, 0, stream>>>(
        hseqB + 16384, fcWB, fc_b, nullptr, out, H_, V_, 1);
}